// Round 12
// baseline (337.254 us; speedup 1.0000x reference)
//
#include <hip/hip_runtime.h>

// ---------------------------------------------------------------------------
// GraphTransformerWithPooling on MI355X (gfx950)
// R12: gather-first reassociation. Each pool layer x <- S(xW+b) is computed
// as (S.prev).W + d*b^T (d = in-degree, free from rpl in LDS). This removes
// the standalone gemm1 (fused1 gathers bf16(x) directly) and fused4 chains
// the Wout GEMM via an LDS round-trip. Gather is latency-bound (4 TB/s eff
// vs ~13 TB/s ceiling; grid doubling was neutral in R9) -> each 16-lane
// group now processes TWO adjacent-ranked nodes with interleaved 4+4 loads
// (dual accumulators) for ~2x per-wave MLP. Degree-ranked pairing from R11.
// 8 dispatches: prep, hist, scan_fuse, fill, fused x4.
// ---------------------------------------------------------------------------

static inline int ceil_div(int a, int b) { return (a + b - 1) / b; }

typedef __attribute__((ext_vector_type(8))) short bf16x8;  // MFMA A/B frag
typedef __attribute__((ext_vector_type(4))) float f32x4;   // MFMA C/D frag

__device__ inline unsigned short f2bf(float f) {   // fp32 -> bf16 RNE
    unsigned u = __float_as_uint(f);
    return (unsigned short)((u + 0x7fffu + ((u >> 16) & 1u)) >> 16);
}

// ---------------- prep: zero cursor/stat, cast x->bf16, W frags -------------
// Frag layout t = ((ct*4+c)*64+lane)*8+j <-> k = c*32+(lane>>4)*8+j,
//   col = ct*16+(lane&15); a wave's 16B load of hi[] is the MFMA B fragment.

__device__ void wprep_dev(const float* __restrict__ W, unsigned short* __restrict__ hi,
                          int total, int C, int g0, int G) {
    for (int t = g0; t < total; t += G) {
        int j = t & 7;
        int lane = (t >> 3) & 63;
        int f = t >> 9;
        int c = f & 3, ct = f >> 2;
        int k = c * 32 + (lane >> 4) * 8 + j;
        int col = ct * 16 + (lane & 15);
        hi[t] = f2bf(W[(size_t)k * C + col]);
    }
}

__global__ __launch_bounds__(256) void prep_kernel(const float* __restrict__ x,
                                                   const float* __restrict__ W1,
                                                   const float* __restrict__ W2,
                                                   const float* __restrict__ Wout,
                                                   unsigned short* __restrict__ xb,
                                                   unsigned short* __restrict__ W1hi,
                                                   unsigned short* __restrict__ W2hi,
                                                   unsigned short* __restrict__ Wohi,
                                                   int* __restrict__ cursor,
                                                   unsigned* __restrict__ stat,
                                                   int N, int nChunks) {
    int g0 = blockIdx.x * 256 + threadIdx.x;
    int G = gridDim.x * 256;
    for (int i = g0; i < N; i += G) cursor[i] = 0;
    for (int i = g0; i < nChunks; i += G) stat[i] = 0;

    int nq = N * 32;   // float4 count of x
    for (int i = g0; i < nq; i += G) {
        float4 v = ((const float4*)x)[i];
        ushort4 o;
        o.x = f2bf(v.x); o.y = f2bf(v.y); o.z = f2bf(v.z); o.w = f2bf(v.w);
        ((ushort4*)xb)[i] = o;
    }

    wprep_dev(W1, W1hi, 128 * 128, 128, g0, G);
    wprep_dev(W2, W2hi, 128 * 128, 128, g0, G);
    wprep_dev(Wout, Wohi, 128 * 64, 64, g0, G);
}

// ---------------- CSR build ----------------

__global__ __launch_bounds__(256) void hist_kernel(const int* __restrict__ dst,
                                                   int* __restrict__ deg, int E) {
    int e = blockIdx.x * 256 + threadIdx.x;
    if (e < E) atomicAdd(&deg[dst[e]], 1);
}

// Merged scan: publish chunk total (flag bit), spin-read predecessors
// (publishers never wait -> no deadlock). Writes rp, seeds fill cursor.
__global__ __launch_bounds__(256) void scan_fuse_kernel(const int* __restrict__ deg,
                                                        int* __restrict__ rp,
                                                        int* __restrict__ cursor,
                                                        unsigned* __restrict__ stat,
                                                        int N) {
    __shared__ int s[256];
    int c = blockIdx.x, tid = threadIdx.x;
    int i = c * 256 + tid;
    int v = (i < N) ? deg[i] : 0;
    s[tid] = v;
    __syncthreads();
    for (int off = 1; off < 256; off <<= 1) {
        int t = (tid >= off) ? s[tid - off] : 0;
        __syncthreads();
        s[tid] += t;
        __syncthreads();
    }
    int loc = s[tid] - v;
    int tot = s[255];
    __syncthreads();
    if (tid == 0) atomicExch(&stat[c], (unsigned)tot | 0x80000000u);

    unsigned mine = 0;
    if (tid < c) {
        unsigned u;
        do { u = atomicAdd(&stat[tid], 0u); } while (!(u & 0x80000000u));
        mine = u & 0x7fffffffu;
    }
    s[tid] = (int)mine;
    __syncthreads();
    for (int off = 128; off >= 1; off >>= 1) {
        if (tid < off) s[tid] += s[tid + off];
        __syncthreads();
    }
    int prefix = s[0];
    if (i <= N) {
        int val = loc + prefix;
        rp[i] = val;
        if (i < N) cursor[i] = val;
    }
}

__global__ __launch_bounds__(256) void fill_kernel(const int* __restrict__ src,
                                                   const int* __restrict__ dst,
                                                   int* __restrict__ cursor,
                                                   unsigned short* __restrict__ es, int E) {
    int e = blockIdx.x * 256 + threadIdx.x;
    if (e < E) {
        int p = atomicAdd(&cursor[dst[e]], 1);
        es[p] = (unsigned short)src[e];
    }
}

// ---------------- Fused: gather -> GEMM (+ d*b^T) [-> ReLU -> Wout GEMM] ----
// Block owns 64 nodes. Rank nodes by degree (64x64 compares); 16-lane group g
// at step q processes the adjacent-rank PAIR perm[2(q*16+g)], perm[2(q*16+g)+1]
// with interleaved 4+4 row loads (dual accumulators -> 2x per-wave MLP).
// Phase B: 4 waves, 64x128 MFMA tile, A from LDS (stride 136, 2-way = free),
// W frags streamed (L2-hot). Epilogue adds deg[row]*b[col] (S(1b^T) = d b^T).
// OUTCHAIN: result -> ReLU -> Hl round-trip -> 64x64 Wout MFMA -> fp32 out.

__device__ inline void acc_row8(float* a, uint4 v) {
    a[0] += __uint_as_float(v.x << 16);
    a[1] += __uint_as_float(v.x & 0xffff0000u);
    a[2] += __uint_as_float(v.y << 16);
    a[3] += __uint_as_float(v.y & 0xffff0000u);
    a[4] += __uint_as_float(v.z << 16);
    a[5] += __uint_as_float(v.z & 0xffff0000u);
    a[6] += __uint_as_float(v.w << 16);
    a[7] += __uint_as_float(v.w & 0xffff0000u);
}

template <bool RELU, bool OUTCHAIN>
__global__ __launch_bounds__(256) void fused_kernel(const unsigned short* __restrict__ M,
                                                    const int* __restrict__ rp,
                                                    const unsigned short* __restrict__ es,
                                                    const uint4* __restrict__ Whi,
                                                    const float* __restrict__ bvec,
                                                    const uint4* __restrict__ Wof,
                                                    const float* __restrict__ bout,
                                                    void* __restrict__ Yv, int n) {
    constexpr int SR = 136;                    // LDS row stride in bf16
    __shared__ unsigned short Hl[64 * SR];
    __shared__ int rpl[65];
    __shared__ unsigned char perm[64];         // rank -> local node index

    int tid = threadIdx.x;
    int r0 = blockIdx.x * 64;

    if (tid < 65) {
        int gi = r0 + tid;
        if (gi > n) gi = n;
        rpl[tid] = rp[gi];
    }
    __syncthreads();

    // rank by degree (desc; ties by index) — 64 threads, 64 compares each
    if (tid < 64) {
        int di = rpl[tid + 1] - rpl[tid];
        int rank = 0;
        for (int j = 0; j < 64; ++j) {
            int dj = rpl[j + 1] - rpl[j];
            rank += (dj > di) || (dj == di && j < tid);
        }
        perm[rank] = (unsigned char)tid;
    }
    __syncthreads();

    // ---- Phase A: dual-node interleaved gather ----
    {
        int g = tid >> 4, ln = tid & 15;
#pragma unroll 1
        for (int q = 0; q < 2; ++q) {
            int pr = (q * 16 + g) * 2;
            int na = perm[pr], nb = perm[pr + 1];
            int ea = rpl[na], enda = rpl[na + 1];
            int eb = rpl[nb], endb = rpl[nb + 1];
            float accA[8] = {}, accB[8] = {};

            // interleaved main loop: 4 rows of A + 4 of B in flight
            while (ea + 4 <= enda && eb + 4 <= endb) {
                int a0 = es[ea], a1 = es[ea + 1], a2 = es[ea + 2], a3 = es[ea + 3];
                int b0 = es[eb], b1 = es[eb + 1], b2 = es[eb + 2], b3 = es[eb + 3];
                uint4 va0 = ((const uint4*)(M + (size_t)a0 * 128))[ln];
                uint4 va1 = ((const uint4*)(M + (size_t)a1 * 128))[ln];
                uint4 va2 = ((const uint4*)(M + (size_t)a2 * 128))[ln];
                uint4 va3 = ((const uint4*)(M + (size_t)a3 * 128))[ln];
                uint4 vb0 = ((const uint4*)(M + (size_t)b0 * 128))[ln];
                uint4 vb1 = ((const uint4*)(M + (size_t)b1 * 128))[ln];
                uint4 vb2 = ((const uint4*)(M + (size_t)b2 * 128))[ln];
                uint4 vb3 = ((const uint4*)(M + (size_t)b3 * 128))[ln];
                acc_row8(accA, va0); acc_row8(accA, va1);
                acc_row8(accA, va2); acc_row8(accA, va3);
                acc_row8(accB, vb0); acc_row8(accB, vb1);
                acc_row8(accB, vb2); acc_row8(accB, vb3);
                ea += 4; eb += 4;
            }
            // drain A
            for (; ea + 4 <= enda; ea += 4) {
                int a0 = es[ea], a1 = es[ea + 1], a2 = es[ea + 2], a3 = es[ea + 3];
                uint4 v0 = ((const uint4*)(M + (size_t)a0 * 128))[ln];
                uint4 v1 = ((const uint4*)(M + (size_t)a1 * 128))[ln];
                uint4 v2 = ((const uint4*)(M + (size_t)a2 * 128))[ln];
                uint4 v3 = ((const uint4*)(M + (size_t)a3 * 128))[ln];
                acc_row8(accA, v0); acc_row8(accA, v1);
                acc_row8(accA, v2); acc_row8(accA, v3);
            }
            for (; ea < enda; ++ea) {
                uint4 v = ((const uint4*)(M + (size_t)es[ea] * 128))[ln];
                acc_row8(accA, v);
            }
            // drain B
            for (; eb + 4 <= endb; eb += 4) {
                int b0 = es[eb], b1 = es[eb + 1], b2 = es[eb + 2], b3 = es[eb + 3];
                uint4 v0 = ((const uint4*)(M + (size_t)b0 * 128))[ln];
                uint4 v1 = ((const uint4*)(M + (size_t)b1 * 128))[ln];
                uint4 v2 = ((const uint4*)(M + (size_t)b2 * 128))[ln];
                uint4 v3 = ((const uint4*)(M + (size_t)b3 * 128))[ln];
                acc_row8(accB, v0); acc_row8(accB, v1);
                acc_row8(accB, v2); acc_row8(accB, v3);
            }
            for (; eb < endb; ++eb) {
                uint4 v = ((const uint4*)(M + (size_t)es[eb] * 128))[ln];
                acc_row8(accB, v);
            }

            uint4 oA, oB;
            oA.x = (unsigned)f2bf(accA[0]) | ((unsigned)f2bf(accA[1]) << 16);
            oA.y = (unsigned)f2bf(accA[2]) | ((unsigned)f2bf(accA[3]) << 16);
            oA.z = (unsigned)f2bf(accA[4]) | ((unsigned)f2bf(accA[5]) << 16);
            oA.w = (unsigned)f2bf(accA[6]) | ((unsigned)f2bf(accA[7]) << 16);
            oB.x = (unsigned)f2bf(accB[0]) | ((unsigned)f2bf(accB[1]) << 16);
            oB.y = (unsigned)f2bf(accB[2]) | ((unsigned)f2bf(accB[3]) << 16);
            oB.z = (unsigned)f2bf(accB[4]) | ((unsigned)f2bf(accB[5]) << 16);
            oB.w = (unsigned)f2bf(accB[6]) | ((unsigned)f2bf(accB[7]) << 16);
            *(uint4*)(&Hl[na * SR + ln * 8]) = oA;
            *(uint4*)(&Hl[nb * SR + ln * 8]) = oB;
        }
    }
    __syncthreads();

    // ---- Phase B: 64x128 MFMA tile, A from LDS ----
    int wave = tid >> 6, lane = tid & 63;
    int lm = lane & 15, lq = lane >> 4;

    f32x4 acc[4][2];
#pragma unroll
    for (int rt = 0; rt < 4; ++rt)
#pragma unroll
        for (int t = 0; t < 2; ++t)
            acc[rt][t] = (f32x4){0.f, 0.f, 0.f, 0.f};

#pragma unroll
    for (int c = 0; c < 4; ++c) {
        bf16x8 afr[4];
#pragma unroll
        for (int rt = 0; rt < 4; ++rt)
            afr[rt] = *(const bf16x8*)(&Hl[(rt * 16 + lm) * SR + c * 32 + lq * 8]);
#pragma unroll
        for (int t = 0; t < 2; ++t) {
            int ct = wave * 2 + t;
            uint4 uh = Whi[(ct * 4 + c) * 64 + lane];
            bf16x8 wh = *(const bf16x8*)&uh;
#pragma unroll
            for (int rt = 0; rt < 4; ++rt)
                acc[rt][t] = __builtin_amdgcn_mfma_f32_16x16x32_bf16(afr[rt], wh, acc[rt][t], 0, 0, 0);
        }
    }

    // C/D layout: col = lane&15, row = lq*4 + reg. Epilogue adds deg*b.
    if (!OUTCHAIN) {
#pragma unroll
        for (int t = 0; t < 2; ++t) {
            int col = (wave * 2 + t) * 16 + lm;
            float bv = bvec[col];
#pragma unroll
            for (int rt = 0; rt < 4; ++rt) {
#pragma unroll
                for (int r = 0; r < 4; ++r) {
                    int rowl = rt * 16 + lq * 4 + r;
                    int row = r0 + rowl;
                    if (row < n) {
                        float deg = (float)(rpl[rowl + 1] - rpl[rowl]);
                        float v = acc[rt][t][r] + deg * bv;
                        if (RELU) v = fmaxf(v, 0.f);
                        ((unsigned short*)Yv)[(size_t)row * 128 + col] = f2bf(v);
                    }
                }
            }
        }
    } else {
        __syncthreads();   // all Hl A-frag reads done before overwrite
#pragma unroll
        for (int t = 0; t < 2; ++t) {
            int col = (wave * 2 + t) * 16 + lm;
            float bv = bvec[col];
#pragma unroll
            for (int rt = 0; rt < 4; ++rt) {
#pragma unroll
                for (int r = 0; r < 4; ++r) {
                    int rowl = rt * 16 + lq * 4 + r;
                    float deg = (float)(rpl[rowl + 1] - rpl[rowl]);
                    float v = acc[rt][t][r] + deg * bv;
                    v = fmaxf(v, 0.f);           // RELU always on the chain
                    Hl[rowl * SR + col] = f2bf(v);
                }
            }
        }
        __syncthreads();

        // Phase C: 64x64 Wout tile; wave = one 16-col tile
        f32x4 acc2[4];
#pragma unroll
        for (int rt = 0; rt < 4; ++rt) acc2[rt] = (f32x4){0.f, 0.f, 0.f, 0.f};

#pragma unroll
        for (int c = 0; c < 4; ++c) {
            bf16x8 afr[4];
#pragma unroll
            for (int rt = 0; rt < 4; ++rt)
                afr[rt] = *(const bf16x8*)(&Hl[(rt * 16 + lm) * SR + c * 32 + lq * 8]);
            uint4 uw = Wof[(wave * 4 + c) * 64 + lane];
            bf16x8 wf = *(const bf16x8*)&uw;
#pragma unroll
            for (int rt = 0; rt < 4; ++rt)
                acc2[rt] = __builtin_amdgcn_mfma_f32_16x16x32_bf16(afr[rt], wf, acc2[rt], 0, 0, 0);
        }

        int col = wave * 16 + lm;
        float bo = bout[col];
#pragma unroll
        for (int rt = 0; rt < 4; ++rt) {
#pragma unroll
            for (int r = 0; r < 4; ++r) {
                int row = r0 + rt * 16 + lq * 4 + r;
                if (row < n)
                    ((float*)Yv)[(size_t)row * 64 + col] = acc2[rt][r] + bo;
            }
        }
    }
}

// ---------------- Launch ----------------

extern "C" void kernel_launch(void* const* d_in, const int* in_sizes, int n_in,
                              void* d_out, int out_size, void* d_ws, size_t ws_size,
                              hipStream_t stream) {
    const float* x    = (const float*)d_in[0];
    const int*   ei   = (const int*)d_in[1];
    const float* W1   = (const float*)d_in[2];
    const float* b1   = (const float*)d_in[3];
    const float* W2   = (const float*)d_in[4];
    const float* b2   = (const float*)d_in[5];
    const float* Wout = (const float*)d_in[6];
    const float* bout = (const float*)d_in[7];
    float*       out  = (float*)d_out;

    const int N = in_sizes[0] / 128;
    const int E = in_sizes[1] / 2;
    const int* src = ei;
    const int* dst = ei + E;

    char* ws = (char*)d_ws;
    auto take = [&](size_t bytes) {
        char* p = ws;
        ws += (bytes + 255) & ~(size_t)255;
        return p;
    };
    unsigned short* xb = (unsigned short*)take((size_t)N * 128 * 2);
    unsigned short* mA = (unsigned short*)take((size_t)N * 128 * 2);
    unsigned short* mB = (unsigned short*)take((size_t)N * 128 * 2);
    unsigned short* W1hi = (unsigned short*)take(128 * 128 * 2);
    unsigned short* W2hi = (unsigned short*)take(128 * 128 * 2);
    unsigned short* Wohi = (unsigned short*)take(128 * 64 * 2);
    int* rp      = (int*)take((size_t)(N + 1) * sizeof(int));
    int* cursor  = (int*)take((size_t)N * sizeof(int));
    unsigned short* es = (unsigned short*)take((size_t)E * sizeof(unsigned short));
    unsigned* stat = (unsigned*)take(4096);

    const int nChunks = ceil_div(N + 1, 256);   // 196 for N=50000 (<=256 required)
    const int tiles64 = ceil_div(N, 64);

    prep_kernel<<<256, 256, 0, stream>>>(x, W1, W2, Wout, xb, W1hi, W2hi, Wohi,
                                         cursor, stat, N, nChunks);
    hist_kernel<<<ceil_div(E, 256), 256, 0, stream>>>(dst, cursor, E);
    scan_fuse_kernel<<<nChunks, 256, 0, stream>>>(cursor, rp, cursor, stat, N);
    fill_kernel<<<ceil_div(E, 256), 256, 0, stream>>>(src, dst, cursor, es, E);

    // x1 = (S xb) W1 + d b1
    fused_kernel<false, false><<<tiles64, 256, 0, stream>>>(
        xb, rp, es, (const uint4*)W1hi, b1, nullptr, nullptr, mA, N);
    // h = relu((S x1) W1 + d b1)
    fused_kernel<true, false><<<tiles64, 256, 0, stream>>>(
        mA, rp, es, (const uint4*)W1hi, b1, nullptr, nullptr, mB, N);
    // h1 = (S h) W2 + d b2
    fused_kernel<false, false><<<tiles64, 256, 0, stream>>>(
        mB, rp, es, (const uint4*)W2hi, b2, nullptr, nullptr, mA, N);
    // out = relu((S h1) W2 + d b2) @ Wout + bout
    fused_kernel<true, true><<<tiles64, 256, 0, stream>>>(
        mA, rp, es, (const uint4*)W2hi, b2, (const uint4*)Wohi, bout, out, N);
}

// Round 13
// 277.199 us; speedup vs baseline: 1.2166x; 1.2166x over previous
//
#include <hip/hip_runtime.h>

// ---------------------------------------------------------------------------
// GraphTransformerWithPooling on MI355X (gfx950)
// R13: R12's gather-first reassociation (pool layer computed as
// (S.prev).W + d*b^T; no standalone gemm1; Wout chained in the last fused
// kernel) with R11's proven Phase-A gather restored (single node per
// 16-lane-group slot, degree-ranked assignment, unroll-8): R12's dual-node
// interleave raised VGPR 60->68 and dropped occupancy 25%->17% (48 us vs 38).
// 8 dispatches: prep, hist, scan_fuse, fill, fused x4.
// bf16 MFMA (16x16x32), single-rounded bf16 W, fp32 accumulation.
// ---------------------------------------------------------------------------

static inline int ceil_div(int a, int b) { return (a + b - 1) / b; }

typedef __attribute__((ext_vector_type(8))) short bf16x8;  // MFMA A/B frag
typedef __attribute__((ext_vector_type(4))) float f32x4;   // MFMA C/D frag

__device__ inline unsigned short f2bf(float f) {   // fp32 -> bf16 RNE
    unsigned u = __float_as_uint(f);
    return (unsigned short)((u + 0x7fffu + ((u >> 16) & 1u)) >> 16);
}

// ---------------- prep: zero cursor/stat, cast x->bf16, W frags -------------
// Frag layout t = ((ct*4+c)*64+lane)*8+j <-> k = c*32+(lane>>4)*8+j,
//   col = ct*16+(lane&15); a wave's 16B load of hi[] is the MFMA B fragment.

__device__ void wprep_dev(const float* __restrict__ W, unsigned short* __restrict__ hi,
                          int total, int C, int g0, int G) {
    for (int t = g0; t < total; t += G) {
        int j = t & 7;
        int lane = (t >> 3) & 63;
        int f = t >> 9;
        int c = f & 3, ct = f >> 2;
        int k = c * 32 + (lane >> 4) * 8 + j;
        int col = ct * 16 + (lane & 15);
        hi[t] = f2bf(W[(size_t)k * C + col]);
    }
}

__global__ __launch_bounds__(256) void prep_kernel(const float* __restrict__ x,
                                                   const float* __restrict__ W1,
                                                   const float* __restrict__ W2,
                                                   const float* __restrict__ Wout,
                                                   unsigned short* __restrict__ xb,
                                                   unsigned short* __restrict__ W1hi,
                                                   unsigned short* __restrict__ W2hi,
                                                   unsigned short* __restrict__ Wohi,
                                                   int* __restrict__ cursor,
                                                   unsigned* __restrict__ stat,
                                                   int N, int nChunks) {
    int g0 = blockIdx.x * 256 + threadIdx.x;
    int G = gridDim.x * 256;
    for (int i = g0; i < N; i += G) cursor[i] = 0;
    for (int i = g0; i < nChunks; i += G) stat[i] = 0;

    int nq = N * 32;   // float4 count of x
    for (int i = g0; i < nq; i += G) {
        float4 v = ((const float4*)x)[i];
        ushort4 o;
        o.x = f2bf(v.x); o.y = f2bf(v.y); o.z = f2bf(v.z); o.w = f2bf(v.w);
        ((ushort4*)xb)[i] = o;
    }

    wprep_dev(W1, W1hi, 128 * 128, 128, g0, G);
    wprep_dev(W2, W2hi, 128 * 128, 128, g0, G);
    wprep_dev(Wout, Wohi, 128 * 64, 64, g0, G);
}

// ---------------- CSR build ----------------

__global__ __launch_bounds__(256) void hist_kernel(const int* __restrict__ dst,
                                                   int* __restrict__ deg, int E) {
    int e = blockIdx.x * 256 + threadIdx.x;
    if (e < E) atomicAdd(&deg[dst[e]], 1);
}

// Merged scan: publish chunk total (flag bit), spin-read predecessors
// (publishers never wait -> no deadlock). Writes rp, seeds fill cursor.
__global__ __launch_bounds__(256) void scan_fuse_kernel(const int* __restrict__ deg,
                                                        int* __restrict__ rp,
                                                        int* __restrict__ cursor,
                                                        unsigned* __restrict__ stat,
                                                        int N) {
    __shared__ int s[256];
    int c = blockIdx.x, tid = threadIdx.x;
    int i = c * 256 + tid;
    int v = (i < N) ? deg[i] : 0;
    s[tid] = v;
    __syncthreads();
    for (int off = 1; off < 256; off <<= 1) {
        int t = (tid >= off) ? s[tid - off] : 0;
        __syncthreads();
        s[tid] += t;
        __syncthreads();
    }
    int loc = s[tid] - v;
    int tot = s[255];
    __syncthreads();
    if (tid == 0) atomicExch(&stat[c], (unsigned)tot | 0x80000000u);

    unsigned mine = 0;
    if (tid < c) {
        unsigned u;
        do { u = atomicAdd(&stat[tid], 0u); } while (!(u & 0x80000000u));
        mine = u & 0x7fffffffu;
    }
    s[tid] = (int)mine;
    __syncthreads();
    for (int off = 128; off >= 1; off >>= 1) {
        if (tid < off) s[tid] += s[tid + off];
        __syncthreads();
    }
    int prefix = s[0];
    if (i <= N) {
        int val = loc + prefix;
        rp[i] = val;
        if (i < N) cursor[i] = val;
    }
}

__global__ __launch_bounds__(256) void fill_kernel(const int* __restrict__ src,
                                                   const int* __restrict__ dst,
                                                   int* __restrict__ cursor,
                                                   unsigned short* __restrict__ es, int E) {
    int e = blockIdx.x * 256 + threadIdx.x;
    if (e < E) {
        int p = atomicAdd(&cursor[dst[e]], 1);
        es[p] = (unsigned short)src[e];
    }
}

// ---------------- Fused: gather -> GEMM (+ d*b^T) [-> ReLU -> Wout GEMM] ----
// Block owns 64 nodes. Rank nodes by degree (64x64 compares in LDS); slot q
// of 16-lane group g processes rank q*16+g -> a wave's 4 lockstep groups get
// adjacent-rank (nearly equal degree) nodes. Gather: bf16 rows, fp32 acc,
// unroll-8, plain LDS stores (stride 136: 2-way aliasing = free).
// Phase B: 4 waves, 64x128 MFMA tile, A from LDS, W frags streamed (L2-hot).
// Epilogue adds deg[row]*b[col] (S(1 b^T) = d b^T).
// OUTCHAIN: result -> ReLU -> Hl round-trip -> 64x64 Wout MFMA -> fp32 out.

__device__ inline void acc_row8(float* a, uint4 v) {
    a[0] += __uint_as_float(v.x << 16);
    a[1] += __uint_as_float(v.x & 0xffff0000u);
    a[2] += __uint_as_float(v.y << 16);
    a[3] += __uint_as_float(v.y & 0xffff0000u);
    a[4] += __uint_as_float(v.z << 16);
    a[5] += __uint_as_float(v.z & 0xffff0000u);
    a[6] += __uint_as_float(v.w << 16);
    a[7] += __uint_as_float(v.w & 0xffff0000u);
}

template <bool RELU, bool OUTCHAIN>
__global__ __launch_bounds__(256) void fused_kernel(const unsigned short* __restrict__ M,
                                                    const int* __restrict__ rp,
                                                    const unsigned short* __restrict__ es,
                                                    const uint4* __restrict__ Whi,
                                                    const float* __restrict__ bvec,
                                                    const uint4* __restrict__ Wof,
                                                    const float* __restrict__ bout,
                                                    void* __restrict__ Yv, int n) {
    constexpr int SR = 136;                    // LDS row stride in bf16
    __shared__ unsigned short Hl[64 * SR];
    __shared__ int rpl[65];
    __shared__ unsigned char perm[64];         // rank -> local node index

    int tid = threadIdx.x;
    int r0 = blockIdx.x * 64;

    if (tid < 65) {
        int gi = r0 + tid;
        if (gi > n) gi = n;
        rpl[tid] = rp[gi];
    }
    __syncthreads();

    // rank by degree (desc; ties by index) — 64 threads, 64 compares each
    if (tid < 64) {
        int di = rpl[tid + 1] - rpl[tid];
        int rank = 0;
        for (int j = 0; j < 64; ++j) {
            int dj = rpl[j + 1] - rpl[j];
            rank += (dj > di) || (dj == di && j < tid);
        }
        perm[rank] = (unsigned char)tid;
    }
    __syncthreads();

    // ---- Phase A: gather; slot q of group g handles rank q*16+g ----
    {
        int g = tid >> 4, ln = tid & 15;
#pragma unroll 1
        for (int q = 0; q < 4; ++q) {
            int nl = perm[q * 16 + g];
            int beg = rpl[nl], end = rpl[nl + 1];
            float acc[8] = {};
            int e = beg;
            for (; e + 8 <= end; e += 8) {
                int s0 = es[e],     s1 = es[e + 1], s2 = es[e + 2], s3 = es[e + 3];
                int s4 = es[e + 4], s5 = es[e + 5], s6 = es[e + 6], s7 = es[e + 7];
                uint4 v0 = ((const uint4*)(M + (size_t)s0 * 128))[ln];
                uint4 v1 = ((const uint4*)(M + (size_t)s1 * 128))[ln];
                uint4 v2 = ((const uint4*)(M + (size_t)s2 * 128))[ln];
                uint4 v3 = ((const uint4*)(M + (size_t)s3 * 128))[ln];
                uint4 v4 = ((const uint4*)(M + (size_t)s4 * 128))[ln];
                uint4 v5 = ((const uint4*)(M + (size_t)s5 * 128))[ln];
                uint4 v6 = ((const uint4*)(M + (size_t)s6 * 128))[ln];
                uint4 v7 = ((const uint4*)(M + (size_t)s7 * 128))[ln];
                acc_row8(acc, v0); acc_row8(acc, v1);
                acc_row8(acc, v2); acc_row8(acc, v3);
                acc_row8(acc, v4); acc_row8(acc, v5);
                acc_row8(acc, v6); acc_row8(acc, v7);
            }
            for (; e + 4 <= end; e += 4) {
                int s0 = es[e], s1 = es[e + 1], s2 = es[e + 2], s3 = es[e + 3];
                uint4 v0 = ((const uint4*)(M + (size_t)s0 * 128))[ln];
                uint4 v1 = ((const uint4*)(M + (size_t)s1 * 128))[ln];
                uint4 v2 = ((const uint4*)(M + (size_t)s2 * 128))[ln];
                uint4 v3 = ((const uint4*)(M + (size_t)s3 * 128))[ln];
                acc_row8(acc, v0); acc_row8(acc, v1);
                acc_row8(acc, v2); acc_row8(acc, v3);
            }
            for (; e < end; ++e) {
                uint4 v = ((const uint4*)(M + (size_t)es[e] * 128))[ln];
                acc_row8(acc, v);
            }
            uint4 o;
            o.x = (unsigned)f2bf(acc[0]) | ((unsigned)f2bf(acc[1]) << 16);
            o.y = (unsigned)f2bf(acc[2]) | ((unsigned)f2bf(acc[3]) << 16);
            o.z = (unsigned)f2bf(acc[4]) | ((unsigned)f2bf(acc[5]) << 16);
            o.w = (unsigned)f2bf(acc[6]) | ((unsigned)f2bf(acc[7]) << 16);
            *(uint4*)(&Hl[nl * SR + ln * 8]) = o;
        }
    }
    __syncthreads();

    // ---- Phase B: 64x128 MFMA tile, A from LDS ----
    int wave = tid >> 6, lane = tid & 63;
    int lm = lane & 15, lq = lane >> 4;

    f32x4 acc[4][2];
#pragma unroll
    for (int rt = 0; rt < 4; ++rt)
#pragma unroll
        for (int t = 0; t < 2; ++t)
            acc[rt][t] = (f32x4){0.f, 0.f, 0.f, 0.f};

#pragma unroll
    for (int c = 0; c < 4; ++c) {
        bf16x8 afr[4];
#pragma unroll
        for (int rt = 0; rt < 4; ++rt)
            afr[rt] = *(const bf16x8*)(&Hl[(rt * 16 + lm) * SR + c * 32 + lq * 8]);
#pragma unroll
        for (int t = 0; t < 2; ++t) {
            int ct = wave * 2 + t;
            uint4 uh = Whi[(ct * 4 + c) * 64 + lane];
            bf16x8 wh = *(const bf16x8*)&uh;
#pragma unroll
            for (int rt = 0; rt < 4; ++rt)
                acc[rt][t] = __builtin_amdgcn_mfma_f32_16x16x32_bf16(afr[rt], wh, acc[rt][t], 0, 0, 0);
        }
    }

    // C/D layout: col = lane&15, row = lq*4 + reg. Epilogue adds deg*b.
    if (!OUTCHAIN) {
#pragma unroll
        for (int t = 0; t < 2; ++t) {
            int col = (wave * 2 + t) * 16 + lm;
            float bv = bvec[col];
#pragma unroll
            for (int rt = 0; rt < 4; ++rt) {
#pragma unroll
                for (int r = 0; r < 4; ++r) {
                    int rowl = rt * 16 + lq * 4 + r;
                    int row = r0 + rowl;
                    if (row < n) {
                        float deg = (float)(rpl[rowl + 1] - rpl[rowl]);
                        float v = acc[rt][t][r] + deg * bv;
                        if (RELU) v = fmaxf(v, 0.f);
                        ((unsigned short*)Yv)[(size_t)row * 128 + col] = f2bf(v);
                    }
                }
            }
        }
    } else {
        __syncthreads();   // all Hl A-frag reads done before overwrite
#pragma unroll
        for (int t = 0; t < 2; ++t) {
            int col = (wave * 2 + t) * 16 + lm;
            float bv = bvec[col];
#pragma unroll
            for (int rt = 0; rt < 4; ++rt) {
#pragma unroll
                for (int r = 0; r < 4; ++r) {
                    int rowl = rt * 16 + lq * 4 + r;
                    float deg = (float)(rpl[rowl + 1] - rpl[rowl]);
                    float v = acc[rt][t][r] + deg * bv;
                    v = fmaxf(v, 0.f);           // ReLU always on the chain
                    Hl[rowl * SR + col] = f2bf(v);
                }
            }
        }
        __syncthreads();

        // Phase C: 64x64 Wout tile; wave = one 16-col tile
        f32x4 acc2[4];
#pragma unroll
        for (int rt = 0; rt < 4; ++rt) acc2[rt] = (f32x4){0.f, 0.f, 0.f, 0.f};

#pragma unroll
        for (int c = 0; c < 4; ++c) {
            bf16x8 afr[4];
#pragma unroll
            for (int rt = 0; rt < 4; ++rt)
                afr[rt] = *(const bf16x8*)(&Hl[(rt * 16 + lm) * SR + c * 32 + lq * 8]);
            uint4 uw = Wof[(wave * 4 + c) * 64 + lane];
            bf16x8 wf = *(const bf16x8*)&uw;
#pragma unroll
            for (int rt = 0; rt < 4; ++rt)
                acc2[rt] = __builtin_amdgcn_mfma_f32_16x16x32_bf16(afr[rt], wf, acc2[rt], 0, 0, 0);
        }

        int col = wave * 16 + lm;
        float bo = bout[col];
#pragma unroll
        for (int rt = 0; rt < 4; ++rt) {
#pragma unroll
            for (int r = 0; r < 4; ++r) {
                int row = r0 + rt * 16 + lq * 4 + r;
                if (row < n)
                    ((float*)Yv)[(size_t)row * 64 + col] = acc2[rt][r] + bo;
            }
        }
    }
}

// ---------------- Launch ----------------

extern "C" void kernel_launch(void* const* d_in, const int* in_sizes, int n_in,
                              void* d_out, int out_size, void* d_ws, size_t ws_size,
                              hipStream_t stream) {
    const float* x    = (const float*)d_in[0];
    const int*   ei   = (const int*)d_in[1];
    const float* W1   = (const float*)d_in[2];
    const float* b1   = (const float*)d_in[3];
    const float* W2   = (const float*)d_in[4];
    const float* b2   = (const float*)d_in[5];
    const float* Wout = (const float*)d_in[6];
    const float* bout = (const float*)d_in[7];
    float*       out  = (float*)d_out;

    const int N = in_sizes[0] / 128;
    const int E = in_sizes[1] / 2;
    const int* src = ei;
    const int* dst = ei + E;

    char* ws = (char*)d_ws;
    auto take = [&](size_t bytes) {
        char* p = ws;
        ws += (bytes + 255) & ~(size_t)255;
        return p;
    };
    unsigned short* xb = (unsigned short*)take((size_t)N * 128 * 2);
    unsigned short* mA = (unsigned short*)take((size_t)N * 128 * 2);
    unsigned short* mB = (unsigned short*)take((size_t)N * 128 * 2);
    unsigned short* W1hi = (unsigned short*)take(128 * 128 * 2);
    unsigned short* W2hi = (unsigned short*)take(128 * 128 * 2);
    unsigned short* Wohi = (unsigned short*)take(128 * 64 * 2);
    int* rp      = (int*)take((size_t)(N + 1) * sizeof(int));
    int* cursor  = (int*)take((size_t)N * sizeof(int));
    unsigned short* es = (unsigned short*)take((size_t)E * sizeof(unsigned short));
    unsigned* stat = (unsigned*)take(4096);

    const int nChunks = ceil_div(N + 1, 256);   // 196 for N=50000 (<=256 required)
    const int tiles64 = ceil_div(N, 64);

    prep_kernel<<<256, 256, 0, stream>>>(x, W1, W2, Wout, xb, W1hi, W2hi, Wohi,
                                         cursor, stat, N, nChunks);
    hist_kernel<<<ceil_div(E, 256), 256, 0, stream>>>(dst, cursor, E);
    scan_fuse_kernel<<<nChunks, 256, 0, stream>>>(cursor, rp, cursor, stat, N);
    fill_kernel<<<ceil_div(E, 256), 256, 0, stream>>>(src, dst, cursor, es, E);

    // x1 = (S xb) W1 + d b1
    fused_kernel<false, false><<<tiles64, 256, 0, stream>>>(
        xb, rp, es, (const uint4*)W1hi, b1, nullptr, nullptr, mA, N);
    // h = relu((S x1) W1 + d b1)
    fused_kernel<true, false><<<tiles64, 256, 0, stream>>>(
        mA, rp, es, (const uint4*)W1hi, b1, nullptr, nullptr, mB, N);
    // h1 = (S h) W2 + d b2
    fused_kernel<false, false><<<tiles64, 256, 0, stream>>>(
        mB, rp, es, (const uint4*)W2hi, b2, nullptr, nullptr, mA, N);
    // out = relu((S h1) W2 + d b2) @ Wout + bout
    fused_kernel<true, true><<<tiles64, 256, 0, stream>>>(
        mA, rp, es, (const uint4*)W2hi, b2, (const uint4*)Wohi, bout, out, N);
}